// Round 2
// baseline (351.606 us; speedup 1.0000x reference)
//
#include <hip/hip_runtime.h>
#include <stdint.h>

typedef unsigned long long u64;
typedef unsigned int u32;

#define N_ANCH 36864
#define WGRID 64
#define A_PER 9
#define KTOP 6000
#define NOUT 300
#define NBIN 32768      // top 15 bits of 64-bit key
#define NMSW 94         // ceil(6000/64) words per NMS mask row

// Base anchors from py-faster-rcnn generate_anchors (scales 8,16,32; ratios .5,1,2), exact integers.
__constant__ float c_ax1[9] = {-84.f,-176.f,-360.f,-56.f,-120.f,-248.f,-36.f,-80.f,-168.f};
__constant__ float c_ay1[9] = {-40.f,-88.f,-184.f,-56.f,-120.f,-248.f,-80.f,-168.f,-344.f};
__constant__ float c_aw[9]  = {184.f,368.f,736.f,128.f,256.f,512.f,88.f,176.f,352.f};
__constant__ float c_ah[9]  = {96.f,192.f,384.f,128.f,256.f,512.f,176.f,352.f,704.f};

__global__ void zero_hist_kernel(u32* __restrict__ hist) {
    int i = blockIdx.x * blockDim.x + threadIdx.x;
    if (i < NBIN) hist[i] = 0;
}

__global__ void proposal_kernel(const float* __restrict__ cls,
                                const float* __restrict__ dlt,
                                u64* __restrict__ keys,
                                float4* __restrict__ boxes,
                                u32* __restrict__ hist) {
    int i = blockIdx.x * blockDim.x + threadIdx.x;
    if (i >= N_ANCH) return;
    int a  = i % A_PER;
    int hw = i / A_PER;
    int wx = hw % WGRID;
    int hy = hw / WGRID;

    // softmax over 2 logits, class-1 prob (matches jax.nn.softmax: subtract max)
    float l0 = cls[hw * 18 + 2 * a];
    float l1 = cls[hw * 18 + 2 * a + 1];
    float m  = fmaxf(l0, l1);
    float e0 = expf(l0 - m), e1 = expf(l1 - m);
    float s  = e1 / (e0 + e1);

    const float* d = dlt + hw * 36 + 4 * a;
    float dx = d[0], dy = d[1], dw = d[2], dh = d[3];
    float aw = c_aw[a], ah = c_ah[a];
    float axc = (c_ax1[a] + 16.f * (float)wx) + 0.5f * aw;
    float ayc = (c_ay1[a] + 16.f * (float)hy) + 0.5f * ah;

    float pxc = dx * aw + axc;
    float pyc = dy * ah + ayc;
    float pw  = expf(dw) * aw;
    float ph  = expf(dh) * ah;
    float x1 = pxc - 0.5f * pw, y1 = pyc - 0.5f * ph;
    float x2 = pxc + 0.5f * pw, y2 = pyc + 0.5f * ph;
    x1 = fminf(fmaxf(x1, 0.f), 1023.f);
    x2 = fminf(fmaxf(x2, 0.f), 1023.f);
    y1 = fminf(fmaxf(y1, 0.f), 1023.f);
    y2 = fminf(fmaxf(y2, 0.f), 1023.f);
    bool valid = ((x2 - x1 + 1.f) >= 16.f) && ((y2 - y1 + 1.f) >= 16.f);
    float sc = valid ? s : -__builtin_huge_valf();

    // order-preserving float->uint; key = (ord(score)<<32) | ~index  (desc score, asc index)
    u32 sb  = __float_as_uint(sc);
    u32 ord = (sb & 0x80000000u) ? ~sb : (sb | 0x80000000u);
    u64 key = ((u64)ord << 32) | (u32)(~(u32)i);
    keys[i]  = key;
    boxes[i] = make_float4(x1, y1, x2, y2);
    atomicAdd(&hist[(u32)(key >> 49)], 1u);
}

// Single block: descending exclusive prefix over 32768 bins -> binStart; find E (end of
// boundary bucket straddling rank 6000); zero cursors; init gV=KTOP.
__global__ __launch_bounds__(1024) void scan_kernel(const u32* __restrict__ hist,
                                                    u32* __restrict__ binStart,
                                                    u32* __restrict__ cursor,
                                                    u32* __restrict__ gEV) {
    __shared__ u32 sh[1024];
    int t = threadIdx.x;
    for (int i = t; i < NBIN; i += 1024) cursor[i] = 0;
    if (t == 0) gEV[1] = KTOP;   // gV init (finite-count; lowered by rank_kernel)
    int hi = NBIN - 1 - 32 * t;  // thread t owns bins [hi-31 .. hi], descending
    u32 cnt[32];
    u32 sum = 0;
#pragma unroll
    for (int k = 0; k < 32; ++k) { cnt[k] = hist[hi - k]; sum += cnt[k]; }
    sh[t] = sum;
    __syncthreads();
    for (int d = 1; d < 1024; d <<= 1) {
        u32 v = (t >= d) ? sh[t - d] : 0;
        __syncthreads();
        sh[t] += v;
        __syncthreads();
    }
    u32 run = sh[t] - sum;   // exclusive (sum of all higher bins)
#pragma unroll
    for (int k = 0; k < 32; ++k) {
        int b = hi - k;
        binStart[b] = run;
        u32 end = run + cnt[k];
        if (run < KTOP && end >= KTOP) gEV[0] = end;   // unique boundary bucket
        run = end;
    }
}

// Scatter keys of buckets that start before rank KTOP into contiguous per-bucket slots.
__global__ void scatter_kernel(const u64* __restrict__ keys,
                               const u32* __restrict__ binStart,
                               u32* __restrict__ cursor,
                               u64* __restrict__ scat) {
    int i = blockIdx.x * blockDim.x + threadIdx.x;
    if (i >= N_ANCH) return;
    u64 k = keys[i];
    u32 b = (u32)(k >> 49);
    u32 s = binStart[b];
    if (s < KTOP) {
        u32 p = s + atomicAdd(&cursor[b], 1u);
        scat[p] = k;
    }
}

// Exact rank within bucket by counting larger keys (keys unique); gather topBoxes[rank].
__global__ void rank_kernel(const u64* __restrict__ scat,
                            const u32* __restrict__ binStart,
                            const u32* __restrict__ hist,
                            const float4* __restrict__ boxes,
                            const u32* __restrict__ gEV,
                            float4* __restrict__ topBoxes,
                            int* __restrict__ gV) {
    int i = blockIdx.x * blockDim.x + threadIdx.x;
    u32 E = gEV[0];
    if (i >= (int)E) return;
    u64 k = scat[i];
    u32 b = (u32)(k >> 49);
    u32 s = binStart[b], c = hist[b];
    u32 r = s;
    for (u32 j = s; j < s + c; ++j) r += (scat[j] > k) ? 1u : 0u;
    if (r < KTOP) {
        int idx = (int)(~(u32)k);
        topBoxes[r] = boxes[idx];
        if (!(k >> 63)) atomicMin(gV, (int)r);   // first -inf rank => V
    }
}

__device__ __forceinline__ bool iou_gt(float4 a, float areaA, float4 b, float areaB) {
    float ix1 = fmaxf(a.x, b.x), iy1 = fmaxf(a.y, b.y);
    float ix2 = fminf(a.z, b.z), iy2 = fminf(a.w, b.w);
    float iw = fmaxf(ix2 - ix1 + 1.0f, 0.0f);
    float ih = fmaxf(iy2 - iy1 + 1.0f, 0.0f);
    float inter = iw * ih;
    float iou = inter / (areaA + areaB - inter);
    return iou > 0.7f;
}

// Grid (94 x 94) blocks x 64 threads: full suppression bitmask matrix.
// mask[i*94 + c] bit j = (global j = c*64+j) > i && IoU(i,j) > 0.7. Words below diagonal = 0.
__global__ __launch_bounds__(64) void mask_kernel(const float4* __restrict__ topBoxes,
                                                  u64* __restrict__ mask) {
    int c = blockIdx.x, r = blockIdx.y;
    int t = threadIdx.x;
    int i = r * 64 + t;
    if (c < r) {                       // block-uniform branch
        if (i < KTOP) mask[(u64)i * NMSW + c] = 0;
        return;
    }
    __shared__ float4 cb[64];
    __shared__ float  ca[64];
    int cbase = c * 64;
    int csz = min(64, KTOP - cbase);
    if (t < csz) {
        float4 bb = topBoxes[cbase + t];
        cb[t] = bb;
        ca[t] = (bb.z - bb.x + 1.f) * (bb.w - bb.y + 1.f);
    }
    __syncthreads();
    if (i >= KTOP) return;
    float4 a = topBoxes[i];
    float aa = (a.z - a.x + 1.f) * (a.w - a.y + 1.f);
    u64 m = 0;
    for (int j = 0; j < csz; ++j) {
        int gj = cbase + j;
        if (gj > i && iou_gt(a, aa, cb[j], ca[j])) m |= (1ULL << j);
    }
    mask[(u64)i * NMSW + c] = m;
}

// Single block, 128 threads: greedy resolve over precomputed masks + output blob.
__global__ __launch_bounds__(128) void nms_out_kernel(const float4* __restrict__ topBoxes,
                                                      const u64* __restrict__ mask,
                                                      const u32* __restrict__ gEV,
                                                      float* __restrict__ out) {
    __shared__ u64 remv[NMSW];
    __shared__ u64 intra[64];
    __shared__ u64 keepw[NMSW];
    __shared__ float4 kbox[NOUT];
    __shared__ u64 s_kb;
    __shared__ int s_nkept, s_old;
    int t = threadIdx.x;
    if (t < NMSW) { remv[t] = 0; keepw[t] = 0; }
    if (t == 0) s_nkept = 0;
    __syncthreads();
    const int V = (int)gEV[1];

    for (int cidx = 0; cidx < NMSW; ++cidx) {
        int base = cidx * 64;
        if (base >= V || s_nkept >= NOUT) break;
        int csz = min(64, V - base);
        if (t < csz) intra[t] = mask[(u64)(base + t) * NMSW + cidx];
        __syncthreads();
        if (t == 0) {
            u64 alive = ~remv[cidx];
            if (csz < 64) alive &= ((1ULL << csz) - 1ULL);
            u64 cand = alive, kb = 0;
            int nk = s_nkept;
            while (cand && nk < NOUT) {
                int b = __builtin_ctzll(cand);
                cand &= cand - 1;
                kb |= (1ULL << b);
                ++nk;
                cand &= ~intra[b];
            }
            keepw[cidx] = kb;
            s_kb = kb; s_old = s_nkept; s_nkept = nk;
        }
        __syncthreads();
        u64 kb = s_kb;
        int old = s_old;
        if (t < NMSW) {                          // OR kept rows into remv (coalesced across t)
            u64 acc = remv[t];
            u64 tmp = kb;
            while (tmp) {
                int b = __builtin_ctzll(tmp);
                tmp &= tmp - 1;
                acc |= mask[(u64)(base + b) * NMSW + t];
            }
            remv[t] = acc;
        }
        if (t < 64 && ((kb >> t) & 1ULL)) {      // append kept boxes in rank order
            int pos = old + __popcll(kb & ((1ULL << t) - 1ULL));
            kbox[pos] = topBoxes[base + t];
        }
        __syncthreads();
    }

    int n1 = s_nkept;
    for (int r = t; r < n1; r += 128) {
        float4 b = kbox[r];
        out[r * 5 + 0] = 0.f;
        out[r * 5 + 1] = b.x; out[r * 5 + 2] = b.y;
        out[r * 5 + 3] = b.z; out[r * 5 + 4] = b.w;
    }
    // fallback: fewer than 300 kept -> remaining slots are -inf ties, ascending rank order
    if (n1 < NOUT && t == 0) {
        int fill = n1;
        for (int r = 0; r < KTOP && fill < NOUT; ++r) {
            bool g1 = (r < V) && ((keepw[r >> 6] >> (r & 63)) & 1ULL);
            if (!g1) {
                float4 b = topBoxes[r];
                out[fill * 5 + 0] = 0.f;
                out[fill * 5 + 1] = b.x; out[fill * 5 + 2] = b.y;
                out[fill * 5 + 3] = b.z; out[fill * 5 + 4] = b.w;
                ++fill;
            }
        }
    }
}

extern "C" void kernel_launch(void* const* d_in, const int* in_sizes, int n_in,
                              void* d_out, int out_size, void* d_ws, size_t ws_size,
                              hipStream_t stream) {
    const float* cls = (const float*)d_in[0];   // (1,64,64,18) f32
    const float* dlt = (const float*)d_in[1];   // (1,64,64,36) f32
    float* out = (float*)d_out;                 // 300x5 f32
    char* ws = (char*)d_ws;
    // layout (16B-aligned offsets)
    u64*    mask     = (u64*)   (ws);                    // 6000*94*8 = 4512000
    u64*    keys     = (u64*)   (ws + 4512000);          // 294912
    u64*    scat     = (u64*)   (ws + 4806912);          // 294912
    float4* boxes    = (float4*)(ws + 5101824);          // 589824
    float4* topBoxes = (float4*)(ws + 5691648);          // 96000
    u32*    hist     = (u32*)   (ws + 5787648);          // 131072
    u32*    binStart = (u32*)   (ws + 5918720);          // 131072
    u32*    cursor   = (u32*)   (ws + 6049792);          // 131072
    u32*    gEV      = (u32*)   (ws + 6180864);          // [0]=E, [1]=V

    zero_hist_kernel<<<32, 1024, 0, stream>>>(hist);
    proposal_kernel<<<(N_ANCH + 255) / 256, 256, 0, stream>>>(cls, dlt, keys, boxes, hist);
    scan_kernel<<<1, 1024, 0, stream>>>(hist, binStart, cursor, gEV);
    scatter_kernel<<<(N_ANCH + 255) / 256, 256, 0, stream>>>(keys, binStart, cursor, scat);
    rank_kernel<<<(N_ANCH + 255) / 256, 256, 0, stream>>>(scat, binStart, hist, boxes, gEV,
                                                          topBoxes, (int*)&gEV[1]);
    mask_kernel<<<dim3(NMSW, NMSW), 64, 0, stream>>>(topBoxes, mask);
    nms_out_kernel<<<1, 128, 0, stream>>>(topBoxes, mask, gEV, out);
}

// Round 3
// 267.282 us; speedup vs baseline: 1.3155x; 1.3155x over previous
//
#include <hip/hip_runtime.h>
#include <stdint.h>

typedef unsigned long long u64;
typedef unsigned int u32;

#define N_ANCH 36864
#define WGRID 64
#define A_PER 9
#define KTOP 6000
#define NOUT 300
#define NBIN 32768      // top 15 bits of 64-bit key
#define NCHK 94         // ceil(6000/64)

// Base anchors from py-faster-rcnn generate_anchors (scales 8,16,32; ratios .5,1,2), exact integers.
__constant__ float c_ax1[9] = {-84.f,-176.f,-360.f,-56.f,-120.f,-248.f,-36.f,-80.f,-168.f};
__constant__ float c_ay1[9] = {-40.f,-88.f,-184.f,-56.f,-120.f,-248.f,-80.f,-168.f,-344.f};
__constant__ float c_aw[9]  = {184.f,368.f,736.f,128.f,256.f,512.f,88.f,176.f,352.f};
__constant__ float c_ah[9]  = {96.f,192.f,384.f,128.f,256.f,512.f,176.f,352.f,704.f};

__global__ void proposal_kernel(const float* __restrict__ cls,
                                const float* __restrict__ dlt,
                                u64* __restrict__ keys,
                                float4* __restrict__ boxes,
                                u32* __restrict__ hist) {
    int i = blockIdx.x * blockDim.x + threadIdx.x;
    if (i >= N_ANCH) return;
    int a  = i % A_PER;
    int hw = i / A_PER;
    int wx = hw % WGRID;
    int hy = hw / WGRID;

    // softmax over 2 logits, class-1 prob (matches jax.nn.softmax: subtract max)
    float l0 = cls[hw * 18 + 2 * a];
    float l1 = cls[hw * 18 + 2 * a + 1];
    float m  = fmaxf(l0, l1);
    float e0 = expf(l0 - m), e1 = expf(l1 - m);
    float s  = e1 / (e0 + e1);

    const float* d = dlt + hw * 36 + 4 * a;
    float dx = d[0], dy = d[1], dw = d[2], dh = d[3];
    float aw = c_aw[a], ah = c_ah[a];
    float axc = (c_ax1[a] + 16.f * (float)wx) + 0.5f * aw;
    float ayc = (c_ay1[a] + 16.f * (float)hy) + 0.5f * ah;

    float pxc = dx * aw + axc;
    float pyc = dy * ah + ayc;
    float pw  = expf(dw) * aw;
    float ph  = expf(dh) * ah;
    float x1 = pxc - 0.5f * pw, y1 = pyc - 0.5f * ph;
    float x2 = pxc + 0.5f * pw, y2 = pyc + 0.5f * ph;
    x1 = fminf(fmaxf(x1, 0.f), 1023.f);
    x2 = fminf(fmaxf(x2, 0.f), 1023.f);
    y1 = fminf(fmaxf(y1, 0.f), 1023.f);
    y2 = fminf(fmaxf(y2, 0.f), 1023.f);
    bool valid = ((x2 - x1 + 1.f) >= 16.f) && ((y2 - y1 + 1.f) >= 16.f);
    float sc = valid ? s : -__builtin_huge_valf();

    // order-preserving float->uint; key = (ord(score)<<32) | ~index  (desc score, asc index)
    u32 sb  = __float_as_uint(sc);
    u32 ord = (sb & 0x80000000u) ? ~sb : (sb | 0x80000000u);
    u64 key = ((u64)ord << 32) | (u32)(~(u32)i);
    keys[i]  = key;
    boxes[i] = make_float4(x1, y1, x2, y2);
    atomicAdd(&hist[(u32)(key >> 49)], 1u);
}

// Single block: descending exclusive prefix over 32768 bins -> binStart; find E (end of
// boundary bucket straddling rank 6000); init gV=KTOP. (cursor zeroed by memset)
__global__ __launch_bounds__(1024) void scan_kernel(const u32* __restrict__ hist,
                                                    u32* __restrict__ binStart,
                                                    u32* __restrict__ gEV) {
    __shared__ u32 sh[1024];
    int t = threadIdx.x;
    if (t == 0) gEV[1] = KTOP;   // V init (lowered by rank_kernel via atomicMin)
    int hi = NBIN - 1 - 32 * t;  // thread t owns bins [hi-31 .. hi], descending
    u32 cnt[32];
    u32 sum = 0;
#pragma unroll
    for (int k = 0; k < 32; ++k) { cnt[k] = hist[hi - k]; sum += cnt[k]; }
    sh[t] = sum;
    __syncthreads();
    for (int d = 1; d < 1024; d <<= 1) {
        u32 v = (t >= d) ? sh[t - d] : 0;
        __syncthreads();
        sh[t] += v;
        __syncthreads();
    }
    u32 run = sh[t] - sum;   // exclusive (sum of all higher bins)
#pragma unroll
    for (int k = 0; k < 32; ++k) {
        int b = hi - k;
        binStart[b] = run;
        u32 end = run + cnt[k];
        if (run < KTOP && end >= KTOP) gEV[0] = end;   // unique boundary bucket
        run = end;
    }
}

// Scatter keys of buckets that start before rank KTOP into contiguous per-bucket slots.
__global__ void scatter_kernel(const u64* __restrict__ keys,
                               const u32* __restrict__ binStart,
                               u32* __restrict__ cursor,
                               u64* __restrict__ scat) {
    int i = blockIdx.x * blockDim.x + threadIdx.x;
    if (i >= N_ANCH) return;
    u64 k = keys[i];
    u32 b = (u32)(k >> 49);
    u32 s = binStart[b];
    if (s < KTOP) {
        u32 p = s + atomicAdd(&cursor[b], 1u);
        scat[p] = k;
    }
}

// Exact rank within bucket by counting larger keys (keys unique); gather topBoxes[rank].
__global__ void rank_kernel(const u64* __restrict__ scat,
                            const u32* __restrict__ binStart,
                            const u32* __restrict__ hist,
                            const float4* __restrict__ boxes,
                            const u32* __restrict__ gEV,
                            float4* __restrict__ topBoxes,
                            int* __restrict__ gV) {
    int i = blockIdx.x * blockDim.x + threadIdx.x;
    u32 E = gEV[0];
    if (i >= (int)E) return;
    u64 k = scat[i];
    u32 b = (u32)(k >> 49);
    u32 s = binStart[b], c = hist[b];
    u32 r = s;
    for (u32 j = s; j < s + c; ++j) r += (scat[j] > k) ? 1u : 0u;
    if (r < KTOP) {
        int idx = (int)(~(u32)k);
        topBoxes[r] = boxes[idx];
        if (!(k >> 63)) atomicMin(gV, (int)r);   // first -inf rank => V
    }
}

__device__ __forceinline__ bool iou_gt(float4 a, float areaA, float4 b, float areaB) {
    float ix1 = fmaxf(a.x, b.x), iy1 = fmaxf(a.y, b.y);
    float ix2 = fminf(a.z, b.z), iy2 = fminf(a.w, b.w);
    float iw = fmaxf(ix2 - ix1 + 1.0f, 0.0f);
    float ih = fmaxf(iy2 - iy1 + 1.0f, 0.0f);
    float inter = iw * ih;
    float iou = inter / (areaA + areaB - inter);
    return iou > 0.7f;
}

// Single block, 1024 threads: fully fused greedy NMS (on-the-fly IoU, no mask matrix),
// early exit at 300 kept, output blob + parallel -inf fallback fill.
__global__ __launch_bounds__(1024) void nms_out_kernel(const float4* __restrict__ topBoxes,
                                                       const u32* __restrict__ gEV,
                                                       float* __restrict__ out) {
    __shared__ float4 cbox[64];
    __shared__ float  ca[64];
    __shared__ float4 kbox[NOUT];
    __shared__ float  karea[NOUT];
    __shared__ u64 s_intra[64];
    __shared__ u64 s_supw[16];
    __shared__ u64 keepw[NCHK];
    __shared__ u32 scanbuf[1024];
    __shared__ u64 s_kb;
    __shared__ int s_nkept, s_old;

    const int t = threadIdx.x;
    const int lane = t & 63;
    const int w = t >> 6;          // 16 waves
    if (t < NCHK) keepw[t] = 0;
    if (t == 0) s_nkept = 0;
    const int V = (int)gEV[1];
    const int nchunks = (V + 63) >> 6;

    // prefetch chunk 0 boxes into registers
    float4 pre = make_float4(0.f, 0.f, 0.f, 0.f);
    if (t < 64 && t < V) pre = topBoxes[t];
    __syncthreads();

    for (int c = 0; c < nchunks; ++c) {
        const int base = c * 64;
        const int csz = min(64, V - base);
        if (t < 64) {
            cbox[t] = pre;
            ca[t] = (pre.z - pre.x + 1.f) * (pre.w - pre.y + 1.f);
            s_intra[t] = 0;
        }
        __syncthreads();                                   // B1: cbox/ca/intra ready
        // issue prefetch for next chunk (latency hidden behind IoU work)
        {
            int nb = base + 64 + t;
            if (t < 64 && nb < V) pre = topBoxes[nb];
        }
        // --- sup-by-kept: wave w tests kept indices k ≡ w (mod 16) for chunk box = lane
        bool sup = false;
        {
            int nk = s_nkept;
            if (lane < csz) {
                float4 bb = cbox[lane]; float ab = ca[lane];
                for (int k = w; k < nk; k += 16) {
                    if (iou_gt(bb, ab, kbox[k], karea[k])) { sup = true; break; }
                }
            }
        }
        u64 bal = __ballot(sup);
        if (lane == 0) s_supw[w] = bal;
        // --- intra-chunk pair mask: thread (i=lane, slice w) covers j>i with j%16==w
        {
            int i0 = lane;
            if (i0 < csz) {
                float4 bb = cbox[i0]; float ab = ca[i0];
                u64 m = 0;
                int j0 = i0 + 1;
                j0 += ((w - j0) % 16 + 16) % 16;           // first j > i with j%16 == w
                for (int j = j0; j < csz; j += 16)
                    if (iou_gt(bb, ab, cbox[j], ca[j])) m |= (1ULL << j);
                if (m) atomicOr(&s_intra[i0], m);
            }
        }
        __syncthreads();                                   // B2: supw + intra ready
        // --- greedy resolve on wave 0: rows in registers, broadcast via shfl
        if (w == 0) {
            u64 row = s_intra[lane];
            u64 sup64 = 0;
#pragma unroll
            for (int q = 0; q < 16; ++q) sup64 |= s_supw[q];
            u64 alive = ~sup64;
            if (csz < 64) alive &= ((1ULL << csz) - 1ULL);
            u64 cand = alive, kb = 0;
            int nk2 = s_nkept;
            while (cand && nk2 < NOUT) {
                int b = __builtin_ctzll(cand);
                cand &= cand - 1;
                kb |= (1ULL << b);
                ++nk2;
                u64 rb = __shfl(row, b, 64);
                cand &= ~rb;
            }
            if (lane == 0) {
                keepw[c] = kb;
                s_kb = kb; s_old = s_nkept; s_nkept = nk2;
            }
        }
        __syncthreads();                                   // B3: kb/nkept visible
        {
            u64 kb = s_kb;
            int old = s_old;
            if (t < 64 && ((kb >> t) & 1ULL)) {            // append kept in rank order
                int pos = old + __popcll(kb & ((1ULL << t) - 1ULL));
                kbox[pos]  = cbox[t];
                karea[pos] = ca[t];
            }
        }
        __syncthreads();                                   // B4: kbox ready for next chunk
        if (s_nkept >= NOUT) break;
    }

    const int n1 = s_nkept;
    for (int r = t; r < n1; r += 1024) {
        float4 b = kbox[r];
        out[r * 5 + 0] = 0.f;
        out[r * 5 + 1] = b.x; out[r * 5 + 2] = b.y;
        out[r * 5 + 3] = b.z; out[r * 5 + 4] = b.w;
    }
    // fallback: <300 kept -> fill with -inf ties (suppressed OR rank>=V), ascending rank.
    if (n1 < NOUT) {
        __syncthreads();
        const int per = 6;                     // 1024*6 >= 6000
        int r0 = t * per, r1 = min(r0 + per, KTOP);
        u32 cnt = 0;
        for (int r = r0; r < r1; ++r)
            cnt += ((keepw[r >> 6] >> (r & 63)) & 1ULL) ? 0u : 1u;
        scanbuf[t] = cnt;
        __syncthreads();
        for (int d = 1; d < 1024; d <<= 1) {
            u32 v = (t >= d) ? scanbuf[t - d] : 0;
            __syncthreads();
            scanbuf[t] += v;
            __syncthreads();
        }
        int ord = n1 + (int)(scanbuf[t] - cnt);   // exclusive prefix of not-kept
        for (int r = r0; r < r1 && ord < NOUT; ++r) {
            if (!((keepw[r >> 6] >> (r & 63)) & 1ULL)) {
                float4 b = topBoxes[r];
                out[ord * 5 + 0] = 0.f;
                out[ord * 5 + 1] = b.x; out[ord * 5 + 2] = b.y;
                out[ord * 5 + 3] = b.z; out[ord * 5 + 4] = b.w;
                ++ord;
            }
        }
    }
}

extern "C" void kernel_launch(void* const* d_in, const int* in_sizes, int n_in,
                              void* d_out, int out_size, void* d_ws, size_t ws_size,
                              hipStream_t stream) {
    const float* cls = (const float*)d_in[0];   // (1,64,64,18) f32
    const float* dlt = (const float*)d_in[1];   // (1,64,64,36) f32
    float* out = (float*)d_out;                 // 300x5 f32
    char* ws = (char*)d_ws;
    // layout (16B-aligned offsets); hist and cursor adjacent -> single memset
    u64*    keys     = (u64*)   (ws);                    // 294912
    u64*    scat     = (u64*)   (ws + 294912);           // 294912
    float4* boxes    = (float4*)(ws + 589824);           // 589824
    float4* topBoxes = (float4*)(ws + 1179648);          // 96000
    u32*    hist     = (u32*)   (ws + 1275648);          // 131072
    u32*    cursor   = (u32*)   (ws + 1406720);          // 131072
    u32*    binStart = (u32*)   (ws + 1537792);          // 131072
    u32*    gEV      = (u32*)   (ws + 1668864);          // [0]=E, [1]=V

    hipMemsetAsync(hist, 0, 2 * NBIN * sizeof(u32), stream);   // hist + cursor
    proposal_kernel<<<(N_ANCH + 255) / 256, 256, 0, stream>>>(cls, dlt, keys, boxes, hist);
    scan_kernel<<<1, 1024, 0, stream>>>(hist, binStart, gEV);
    scatter_kernel<<<(N_ANCH + 255) / 256, 256, 0, stream>>>(keys, binStart, cursor, scat);
    rank_kernel<<<(N_ANCH + 255) / 256, 256, 0, stream>>>(scat, binStart, hist, boxes, gEV,
                                                          topBoxes, (int*)&gEV[1]);
    nms_out_kernel<<<1, 1024, 0, stream>>>(topBoxes, gEV, out);
}

// Round 4
// 236.933 us; speedup vs baseline: 1.4840x; 1.1281x over previous
//
#include <hip/hip_runtime.h>
#include <stdint.h>

typedef unsigned long long u64;
typedef unsigned int u32;

#define N_ANCH 36864
#define WGRID 64
#define A_PER 9
#define KTOP 6000
#define NOUT 300
#define NBIN 8192       // top 13 bits of 64-bit key
#define BINSHIFT 51
#define NCHK 94         // ceil(6000/64)
#define INF_BIN 15      // bin of ord(-inf) = 0x007FFFFF >> (BINSHIFT-32-... ) == 15

// Base anchors from py-faster-rcnn generate_anchors (scales 8,16,32; ratios .5,1,2), exact integers.
__constant__ float c_ax1[9] = {-84.f,-176.f,-360.f,-56.f,-120.f,-248.f,-36.f,-80.f,-168.f};
__constant__ float c_ay1[9] = {-40.f,-88.f,-184.f,-56.f,-120.f,-248.f,-80.f,-168.f,-344.f};
__constant__ float c_aw[9]  = {184.f,368.f,736.f,128.f,256.f,512.f,88.f,176.f,352.f};
__constant__ float c_ah[9]  = {96.f,192.f,384.f,128.f,256.f,512.f,176.f,352.f,704.f};

// 36 blocks x 1024 threads = 36864. Per-block LDS histogram kills the global
// same-address atomic serialization (the -inf bin alone had ~5k collisions).
__global__ __launch_bounds__(1024) void proposal_kernel(const float* __restrict__ cls,
                                                        const float* __restrict__ dlt,
                                                        u64* __restrict__ keys,
                                                        float4* __restrict__ boxes,
                                                        u32* __restrict__ hist) {
    __shared__ u32 lh[NBIN];
    const int t = threadIdx.x;
    for (int b = t; b < NBIN; b += 1024) lh[b] = 0;
    __syncthreads();

    int i = blockIdx.x * 1024 + t;
    int a  = i % A_PER;
    int hw = i / A_PER;
    int wx = hw % WGRID;
    int hy = hw / WGRID;

    // softmax over 2 logits, class-1 prob (matches jax.nn.softmax: subtract max)
    float l0 = cls[hw * 18 + 2 * a];
    float l1 = cls[hw * 18 + 2 * a + 1];
    float m  = fmaxf(l0, l1);
    float e0 = expf(l0 - m), e1 = expf(l1 - m);
    float s  = e1 / (e0 + e1);

    const float* d = dlt + hw * 36 + 4 * a;
    float dx = d[0], dy = d[1], dw = d[2], dh = d[3];
    float aw = c_aw[a], ah = c_ah[a];
    float axc = (c_ax1[a] + 16.f * (float)wx) + 0.5f * aw;
    float ayc = (c_ay1[a] + 16.f * (float)hy) + 0.5f * ah;

    float pxc = dx * aw + axc;
    float pyc = dy * ah + ayc;
    float pw  = expf(dw) * aw;
    float ph  = expf(dh) * ah;
    float x1 = pxc - 0.5f * pw, y1 = pyc - 0.5f * ph;
    float x2 = pxc + 0.5f * pw, y2 = pyc + 0.5f * ph;
    x1 = fminf(fmaxf(x1, 0.f), 1023.f);
    x2 = fminf(fmaxf(x2, 0.f), 1023.f);
    y1 = fminf(fmaxf(y1, 0.f), 1023.f);
    y2 = fminf(fmaxf(y2, 0.f), 1023.f);
    bool valid = ((x2 - x1 + 1.f) >= 16.f) && ((y2 - y1 + 1.f) >= 16.f);
    float sc = valid ? s : -__builtin_huge_valf();

    // order-preserving float->uint; key = (ord(score)<<32) | ~index  (desc score, asc index)
    u32 sb  = __float_as_uint(sc);
    u32 ord = (sb & 0x80000000u) ? ~sb : (sb | 0x80000000u);
    u64 key = ((u64)ord << 32) | (u32)(~(u32)i);
    keys[i]  = key;
    boxes[i] = make_float4(x1, y1, x2, y2);

    // histogram: wave-aggregate the -inf bin, LDS atomics for the rest
    u64 infb = __ballot(!valid);
    if (valid) {
        atomicAdd(&lh[(u32)(key >> BINSHIFT)], 1u);
    } else {
        int lane = t & 63;
        if (lane == __builtin_ctzll(infb))          // first invalid lane in wave
            atomicAdd(&lh[INF_BIN], (u32)__popcll(infb));
    }
    __syncthreads();
    for (int b = t; b < NBIN; b += 1024) {
        u32 v = lh[b];
        if (v) atomicAdd(&hist[b], v);
    }
}

// Single block: descending exclusive prefix over 8192 bins -> binStart; find E (end of
// boundary bucket straddling rank 6000); init gV=KTOP. (cursor zeroed by memset)
__global__ __launch_bounds__(1024) void scan_kernel(const u32* __restrict__ hist,
                                                    u32* __restrict__ binStart,
                                                    u32* __restrict__ gEV) {
    __shared__ u32 sh[1024];
    int t = threadIdx.x;
    if (t == 0) gEV[1] = KTOP;   // V init (lowered by rank_kernel via atomicMin)
    int hi = NBIN - 1 - 8 * t;   // thread t owns bins [hi-7 .. hi], descending
    u32 cnt[8];
    u32 sum = 0;
#pragma unroll
    for (int k = 0; k < 8; ++k) { cnt[k] = hist[hi - k]; sum += cnt[k]; }
    sh[t] = sum;
    __syncthreads();
    for (int d = 1; d < 1024; d <<= 1) {
        u32 v = (t >= d) ? sh[t - d] : 0;
        __syncthreads();
        sh[t] += v;
        __syncthreads();
    }
    u32 run = sh[t] - sum;   // exclusive (sum of all higher bins)
#pragma unroll
    for (int k = 0; k < 8; ++k) {
        int b = hi - k;
        binStart[b] = run;
        u32 end = run + cnt[k];
        if (run < KTOP && end >= KTOP) gEV[0] = end;   // unique boundary bucket
        run = end;
    }
}

// Scatter keys of buckets that start before rank KTOP into contiguous per-bucket slots.
__global__ void scatter_kernel(const u64* __restrict__ keys,
                               const u32* __restrict__ binStart,
                               u32* __restrict__ cursor,
                               u64* __restrict__ scat) {
    int i = blockIdx.x * blockDim.x + threadIdx.x;
    if (i >= N_ANCH) return;
    u64 k = keys[i];
    u32 b = (u32)(k >> BINSHIFT);
    u32 s = binStart[b];
    if (s < KTOP) {
        u32 p = s + atomicAdd(&cursor[b], 1u);
        scat[p] = k;
    }
}

// Exact rank within bucket by counting larger keys (keys unique); gather topBoxes[rank].
__global__ void rank_kernel(const u64* __restrict__ scat,
                            const u32* __restrict__ binStart,
                            const u32* __restrict__ hist,
                            const float4* __restrict__ boxes,
                            const u32* __restrict__ gEV,
                            float4* __restrict__ topBoxes,
                            int* __restrict__ gV) {
    int i = blockIdx.x * blockDim.x + threadIdx.x;
    u32 E = gEV[0];
    if (i >= (int)E) return;
    u64 k = scat[i];
    u32 b = (u32)(k >> BINSHIFT);
    u32 s = binStart[b], c = hist[b];
    u32 r = s;
    for (u32 j = s; j < s + c; ++j) r += (scat[j] > k) ? 1u : 0u;
    if (r < KTOP) {
        int idx = (int)(~(u32)k);
        topBoxes[r] = boxes[idx];
        if (!(k >> 63)) atomicMin(gV, (int)r);   // first -inf rank => V
    }
}

__device__ __forceinline__ bool iou_gt(float4 a, float areaA, float4 b, float areaB) {
    float ix1 = fmaxf(a.x, b.x), iy1 = fmaxf(a.y, b.y);
    float ix2 = fminf(a.z, b.z), iy2 = fminf(a.w, b.w);
    float iw = fmaxf(ix2 - ix1 + 1.0f, 0.0f);
    float ih = fmaxf(iy2 - iy1 + 1.0f, 0.0f);
    float inter = iw * ih;
    float iou = inter / (areaA + areaB - inter);
    return iou > 0.7f;
}

// Single block, 1024 threads: fused greedy NMS, 2 barriers/chunk (double-buffered chunk
// staging overlapped with wave-0 resolve), early exit at 300 kept, parallel fallback fill.
__global__ __launch_bounds__(1024) void nms_out_kernel(const float4* __restrict__ topBoxes,
                                                       const u32* __restrict__ gEV,
                                                       float* __restrict__ out) {
    __shared__ float4 cbox[2][64];
    __shared__ float  ca[2][64];
    __shared__ u64    intra[2][64];
    __shared__ u64    supw[16];
    __shared__ u64    keepw[NCHK];
    __shared__ float4 kbox[NOUT];
    __shared__ float  karea[NOUT];
    __shared__ u32    scanbuf[1024];
    __shared__ int    s_nkept;

    const int t = threadIdx.x;
    const int lane = t & 63;
    const int w = t >> 6;          // 16 waves
    if (t < NCHK) keepw[t] = 0;
    if (t == 0) s_nkept = 0;
    const int V = (int)gEV[1];
    const int nchunks = (V + 63) >> 6;

    // stage chunk 0
    if (t < 64) {
        float4 b = make_float4(0.f, 0.f, 0.f, 0.f);
        if (t < V) b = topBoxes[t];
        cbox[0][t] = b;
        ca[0][t]   = (b.z - b.x + 1.f) * (b.w - b.y + 1.f);
        intra[0][t] = 0;
    }
    __syncthreads();

    for (int c = 0; c < nchunks; ++c) {
        const int p = c & 1;
        const int base = c * 64;
        const int csz = min(64, V - base);
        const int nk = s_nkept;
        // --- sup-by-kept: wave w tests kept indices k ≡ w (mod 16) for chunk box = lane
        bool sup = false;
        if (lane < csz) {
            float4 bb = cbox[p][lane]; float ab = ca[p][lane];
            for (int k = w; k < nk; k += 16) {
                if (iou_gt(bb, ab, kbox[k], karea[k])) { sup = true; break; }
            }
        }
        u64 bal = __ballot(sup);
        if (lane == 0) supw[w] = bal;
        // --- intra-chunk pair mask: thread (i=lane, slice w) covers j>i with j%16==w
        if (lane < csz) {
            float4 bb = cbox[p][lane]; float ab = ca[p][lane];
            u64 m = 0;
            int j0 = lane + 1;
            j0 += ((w - j0) % 16 + 16) % 16;           // first j > lane with j%16 == w
            for (int j = j0; j < csz; j += 16)
                if (iou_gt(bb, ab, cbox[p][j], ca[p][j])) m |= (1ULL << j);
            if (m) atomicOr(&intra[p][lane], m);
        }
        __syncthreads();                                   // B2: supw + intra ready
        if (w == 0) {
            // --- greedy resolve: rows in registers, broadcast via shfl; kb uniform
            u64 row = intra[p][lane];
            u64 sup64 = 0;
#pragma unroll
            for (int q = 0; q < 16; ++q) sup64 |= supw[q];
            u64 alive = ~sup64;
            if (csz < 64) alive &= ((1ULL << csz) - 1ULL);
            u64 cand = alive, kb = 0;
            const int nk_base = s_nkept;
            int nk2 = nk_base;
            while (cand && nk2 < NOUT) {
                int b = __builtin_ctzll(cand);
                cand &= cand - 1;
                kb |= (1ULL << b);
                ++nk2;
                cand &= ~__shfl(row, b, 64);
            }
            // append kept in rank order (kb identical across wave-0 lanes)
            if ((kb >> lane) & 1ULL) {
                int pos = nk_base + __popcll(kb & ((1ULL << lane) - 1ULL));
                kbox[pos]  = cbox[p][lane];
                karea[pos] = ca[p][lane];
            }
            if (lane == 0) { keepw[c] = kb; s_nkept = nk2; }
        } else if (w == 1) {
            // --- stage next chunk concurrently with resolve
            int nb = base + 64 + lane;
            float4 b = make_float4(0.f, 0.f, 0.f, 0.f);
            if (nb < V) b = topBoxes[nb];
            cbox[p ^ 1][lane] = b;
            ca[p ^ 1][lane]   = (b.z - b.x + 1.f) * (b.w - b.y + 1.f);
            intra[p ^ 1][lane] = 0;
        }
        __syncthreads();                                   // B3: resolve+append+stage done
        if (s_nkept >= NOUT) break;
    }

    const int n1 = s_nkept;
    for (int r = t; r < n1; r += 1024) {
        float4 b = kbox[r];
        out[r * 5 + 0] = 0.f;
        out[r * 5 + 1] = b.x; out[r * 5 + 2] = b.y;
        out[r * 5 + 3] = b.z; out[r * 5 + 4] = b.w;
    }
    // fallback: <300 kept -> fill with -inf ties (suppressed OR rank>=V), ascending rank.
    if (n1 < NOUT) {
        __syncthreads();
        const int per = 6;                     // 1024*6 >= 6000
        int r0 = t * per, r1 = min(r0 + per, KTOP);
        u32 cnt = 0;
        for (int r = r0; r < r1; ++r)
            cnt += ((keepw[r >> 6] >> (r & 63)) & 1ULL) ? 0u : 1u;
        scanbuf[t] = cnt;
        __syncthreads();
        for (int d = 1; d < 1024; d <<= 1) {
            u32 v = (t >= d) ? scanbuf[t - d] : 0;
            __syncthreads();
            scanbuf[t] += v;
            __syncthreads();
        }
        int ord = n1 + (int)(scanbuf[t] - cnt);   // exclusive prefix of not-kept
        for (int r = r0; r < r1 && ord < NOUT; ++r) {
            if (!((keepw[r >> 6] >> (r & 63)) & 1ULL)) {
                float4 b = topBoxes[r];
                out[ord * 5 + 0] = 0.f;
                out[ord * 5 + 1] = b.x; out[ord * 5 + 2] = b.y;
                out[ord * 5 + 3] = b.z; out[ord * 5 + 4] = b.w;
                ++ord;
            }
        }
    }
}

extern "C" void kernel_launch(void* const* d_in, const int* in_sizes, int n_in,
                              void* d_out, int out_size, void* d_ws, size_t ws_size,
                              hipStream_t stream) {
    const float* cls = (const float*)d_in[0];   // (1,64,64,18) f32
    const float* dlt = (const float*)d_in[1];   // (1,64,64,36) f32
    float* out = (float*)d_out;                 // 300x5 f32
    char* ws = (char*)d_ws;
    // layout (16B-aligned offsets); hist and cursor adjacent -> single memset
    u64*    keys     = (u64*)   (ws);                    // 294912
    u64*    scat     = (u64*)   (ws + 294912);           // 294912
    float4* boxes    = (float4*)(ws + 589824);           // 589824
    float4* topBoxes = (float4*)(ws + 1179648);          // 96000
    u32*    hist     = (u32*)   (ws + 1275648);          // 32768
    u32*    cursor   = (u32*)   (ws + 1308416);          // 32768
    u32*    binStart = (u32*)   (ws + 1341184);          // 32768
    u32*    gEV      = (u32*)   (ws + 1373952);          // [0]=E, [1]=V

    hipMemsetAsync(hist, 0, 2 * NBIN * sizeof(u32), stream);   // hist + cursor
    proposal_kernel<<<36, 1024, 0, stream>>>(cls, dlt, keys, boxes, hist);
    scan_kernel<<<1, 1024, 0, stream>>>(hist, binStart, gEV);
    scatter_kernel<<<(N_ANCH + 255) / 256, 256, 0, stream>>>(keys, binStart, cursor, scat);
    rank_kernel<<<(N_ANCH + 255) / 256, 256, 0, stream>>>(scat, binStart, hist, boxes, gEV,
                                                          topBoxes, (int*)&gEV[1]);
    nms_out_kernel<<<1, 1024, 0, stream>>>(topBoxes, gEV, out);
}

// Round 5
// 118.174 us; speedup vs baseline: 2.9753x; 2.0049x over previous
//
#include <hip/hip_runtime.h>
#include <stdint.h>

typedef unsigned long long u64;
typedef unsigned int u32;

#define N_ANCH 36864
#define WGRID 64
#define A_PER 9
#define KTOP 6000
#define NOUT 300
#define NBIN 8192       // bins from distribution-aware monotone map (max used bin = 4352)
#define NCHK 94         // ceil(6000/64)
#define INF_BIN 0       // -inf / invalid scores

// Base anchors from py-faster-rcnn generate_anchors (scales 8,16,32; ratios .5,1,2), exact integers.
__constant__ float c_ax1[9] = {-84.f,-176.f,-360.f,-56.f,-120.f,-248.f,-36.f,-80.f,-168.f};
__constant__ float c_ay1[9] = {-40.f,-88.f,-184.f,-56.f,-120.f,-248.f,-80.f,-168.f,-344.f};
__constant__ float c_aw[9]  = {184.f,368.f,736.f,128.f,256.f,512.f,88.f,176.f,352.f};
__constant__ float c_ah[9]  = {96.f,192.f,384.f,128.f,256.f,512.f,176.f,352.f,704.f};

// Monotone (order-preserving) bin of the ordered-float score word u = key>>32.
// Scores sigmoid(l1-l0) concentrate in [0.5,1) = ONE float octave -> give that
// octave 4096 bins (12 mantissa bits); everything below is coarse and can never
// straddle the rank-6000 boundary (~15500 of ~31000 valid scores are >= 0.5).
__device__ __forceinline__ u32 binof(u32 u) {
    if (u < 0x80000000u) return 0u;                          // -inf (invalid)
    if (u < 0xBF000000u) return 1u + ((u - 0x80000000u) >> 22);   // s<0.5 : 1..252
    return 256u + ((u - 0xBF000000u) >> 11);                 // s>=0.5: 256..4352
}

// 36 blocks x 1024 threads = 36864. Per-block LDS histogram (32 KB).
__global__ __launch_bounds__(1024) void proposal_kernel(const float* __restrict__ cls,
                                                        const float* __restrict__ dlt,
                                                        u64* __restrict__ keys,
                                                        float4* __restrict__ boxes,
                                                        u32* __restrict__ hist) {
    __shared__ u32 lh[NBIN];
    const int t = threadIdx.x;
    for (int b = t; b < NBIN; b += 1024) lh[b] = 0;
    __syncthreads();

    int i = blockIdx.x * 1024 + t;
    int a  = i % A_PER;
    int hw = i / A_PER;
    int wx = hw % WGRID;
    int hy = hw / WGRID;

    // softmax over 2 logits, class-1 prob (matches jax.nn.softmax: subtract max)
    float l0 = cls[hw * 18 + 2 * a];
    float l1 = cls[hw * 18 + 2 * a + 1];
    float m  = fmaxf(l0, l1);
    float e0 = expf(l0 - m), e1 = expf(l1 - m);
    float s  = e1 / (e0 + e1);

    const float* d = dlt + hw * 36 + 4 * a;
    float dx = d[0], dy = d[1], dw = d[2], dh = d[3];
    float aw = c_aw[a], ah = c_ah[a];
    float axc = (c_ax1[a] + 16.f * (float)wx) + 0.5f * aw;
    float ayc = (c_ay1[a] + 16.f * (float)hy) + 0.5f * ah;

    float pxc = dx * aw + axc;
    float pyc = dy * ah + ayc;
    float pw  = expf(dw) * aw;
    float ph  = expf(dh) * ah;
    float x1 = pxc - 0.5f * pw, y1 = pyc - 0.5f * ph;
    float x2 = pxc + 0.5f * pw, y2 = pyc + 0.5f * ph;
    x1 = fminf(fmaxf(x1, 0.f), 1023.f);
    x2 = fminf(fmaxf(x2, 0.f), 1023.f);
    y1 = fminf(fmaxf(y1, 0.f), 1023.f);
    y2 = fminf(fmaxf(y2, 0.f), 1023.f);
    bool valid = ((x2 - x1 + 1.f) >= 16.f) && ((y2 - y1 + 1.f) >= 16.f);
    float sc = valid ? s : -__builtin_huge_valf();

    // order-preserving float->uint; key = (ord(score)<<32) | ~index  (desc score, asc index)
    u32 sb  = __float_as_uint(sc);
    u32 ord = (sb & 0x80000000u) ? ~sb : (sb | 0x80000000u);
    u64 key = ((u64)ord << 32) | (u32)(~(u32)i);
    keys[i]  = key;
    boxes[i] = make_float4(x1, y1, x2, y2);

    // histogram: wave-aggregate the -inf bin, LDS atomics for the rest
    u64 infb = __ballot(!valid);
    if (valid) {
        atomicAdd(&lh[binof(ord)], 1u);
    } else {
        int lane = t & 63;
        if (lane == __builtin_ctzll(infb))          // first invalid lane in wave
            atomicAdd(&lh[INF_BIN], (u32)__popcll(infb));
    }
    __syncthreads();
    for (int b = t; b < NBIN; b += 1024) {
        u32 v = lh[b];
        if (v) atomicAdd(&hist[b], v);
    }
}

// Single block: descending exclusive prefix over 8192 bins -> binStart; find E (end of
// boundary bucket straddling rank 6000); init gV=KTOP. (cursor zeroed by memset)
__global__ __launch_bounds__(1024) void scan_kernel(const u32* __restrict__ hist,
                                                    u32* __restrict__ binStart,
                                                    u32* __restrict__ gEV) {
    __shared__ u32 sh[1024];
    int t = threadIdx.x;
    if (t == 0) gEV[1] = KTOP;   // V init (lowered by rank_kernel via atomicMin)
    int hi = NBIN - 1 - 8 * t;   // thread t owns bins [hi-7 .. hi], descending
    u32 cnt[8];
    u32 sum = 0;
#pragma unroll
    for (int k = 0; k < 8; ++k) { cnt[k] = hist[hi - k]; sum += cnt[k]; }
    sh[t] = sum;
    __syncthreads();
    for (int d = 1; d < 1024; d <<= 1) {
        u32 v = (t >= d) ? sh[t - d] : 0;
        __syncthreads();
        sh[t] += v;
        __syncthreads();
    }
    u32 run = sh[t] - sum;   // exclusive (sum of all higher bins)
#pragma unroll
    for (int k = 0; k < 8; ++k) {
        int b = hi - k;
        binStart[b] = run;
        u32 end = run + cnt[k];
        if (run < KTOP && end >= KTOP) gEV[0] = end;   // unique boundary bucket
        run = end;
    }
}

// Scatter keys of buckets that start before rank KTOP into contiguous per-bucket slots.
__global__ void scatter_kernel(const u64* __restrict__ keys,
                               const u32* __restrict__ binStart,
                               u32* __restrict__ cursor,
                               u64* __restrict__ scat) {
    int i = blockIdx.x * blockDim.x + threadIdx.x;
    if (i >= N_ANCH) return;
    u64 k = keys[i];
    u32 b = binof((u32)(k >> 32));
    u32 s = binStart[b];
    if (s < KTOP) {
        u32 p = s + atomicAdd(&cursor[b], 1u);
        scat[p] = k;
    }
}

// Exact rank within bucket by counting larger keys (keys unique); gather topBoxes[rank].
__global__ void rank_kernel(const u64* __restrict__ scat,
                            const u32* __restrict__ binStart,
                            const u32* __restrict__ hist,
                            const float4* __restrict__ boxes,
                            const u32* __restrict__ gEV,
                            float4* __restrict__ topBoxes,
                            int* __restrict__ gV) {
    int i = blockIdx.x * blockDim.x + threadIdx.x;
    u32 E = gEV[0];
    if (i >= (int)E) return;
    u64 k = scat[i];
    u32 b = binof((u32)(k >> 32));
    u32 s = binStart[b], c = hist[b];
    u32 r = s;
    for (u32 j = s; j < s + c; ++j) r += (scat[j] > k) ? 1u : 0u;
    if (r < KTOP) {
        int idx = (int)(~(u32)k);
        topBoxes[r] = boxes[idx];
        if (!(k >> 63)) atomicMin(gV, (int)r);   // first -inf rank => V
    }
}

__device__ __forceinline__ bool iou_gt(float4 a, float areaA, float4 b, float areaB) {
    float ix1 = fmaxf(a.x, b.x), iy1 = fmaxf(a.y, b.y);
    float ix2 = fminf(a.z, b.z), iy2 = fminf(a.w, b.w);
    float iw = fmaxf(ix2 - ix1 + 1.0f, 0.0f);
    float ih = fmaxf(iy2 - iy1 + 1.0f, 0.0f);
    float inter = iw * ih;
    float iou = inter / (areaA + areaB - inter);
    return iou > 0.7f;
}

// Single block, 1024 threads: fused greedy NMS, 2 barriers/chunk (double-buffered chunk
// staging overlapped with wave-0 resolve), early exit at 300 kept, parallel fallback fill.
__global__ __launch_bounds__(1024) void nms_out_kernel(const float4* __restrict__ topBoxes,
                                                       const u32* __restrict__ gEV,
                                                       float* __restrict__ out) {
    __shared__ float4 cbox[2][64];
    __shared__ float  ca[2][64];
    __shared__ u64    intra[2][64];
    __shared__ u64    supw[16];
    __shared__ u64    keepw[NCHK];
    __shared__ float4 kbox[NOUT];
    __shared__ float  karea[NOUT];
    __shared__ u32    scanbuf[1024];
    __shared__ int    s_nkept;

    const int t = threadIdx.x;
    const int lane = t & 63;
    const int w = t >> 6;          // 16 waves
    if (t < NCHK) keepw[t] = 0;
    if (t == 0) s_nkept = 0;
    const int V = (int)gEV[1];
    const int nchunks = (V + 63) >> 6;

    // stage chunk 0
    if (t < 64) {
        float4 b = make_float4(0.f, 0.f, 0.f, 0.f);
        if (t < V) b = topBoxes[t];
        cbox[0][t] = b;
        ca[0][t]   = (b.z - b.x + 1.f) * (b.w - b.y + 1.f);
        intra[0][t] = 0;
    }
    __syncthreads();

    for (int c = 0; c < nchunks; ++c) {
        const int p = c & 1;
        const int base = c * 64;
        const int csz = min(64, V - base);
        const int nk = s_nkept;
        // --- sup-by-kept: wave w tests kept indices k ≡ w (mod 16) for chunk box = lane
        bool sup = false;
        if (lane < csz) {
            float4 bb = cbox[p][lane]; float ab = ca[p][lane];
            for (int k = w; k < nk; k += 16) {
                if (iou_gt(bb, ab, kbox[k], karea[k])) { sup = true; break; }
            }
        }
        u64 bal = __ballot(sup);
        if (lane == 0) supw[w] = bal;
        // --- intra-chunk pair mask: thread (i=lane, slice w) covers j>i with j%16==w
        if (lane < csz) {
            float4 bb = cbox[p][lane]; float ab = ca[p][lane];
            u64 m = 0;
            int j0 = lane + 1;
            j0 += ((w - j0) % 16 + 16) % 16;           // first j > lane with j%16 == w
            for (int j = j0; j < csz; j += 16)
                if (iou_gt(bb, ab, cbox[p][j], ca[p][j])) m |= (1ULL << j);
            if (m) atomicOr(&intra[p][lane], m);
        }
        __syncthreads();                                   // B2: supw + intra ready
        if (w == 0) {
            // --- greedy resolve: rows in registers, broadcast via shfl; kb uniform
            u64 row = intra[p][lane];
            u64 sup64 = 0;
#pragma unroll
            for (int q = 0; q < 16; ++q) sup64 |= supw[q];
            u64 alive = ~sup64;
            if (csz < 64) alive &= ((1ULL << csz) - 1ULL);
            u64 cand = alive, kb = 0;
            const int nk_base = s_nkept;
            int nk2 = nk_base;
            while (cand && nk2 < NOUT) {
                int b = __builtin_ctzll(cand);
                cand &= cand - 1;
                kb |= (1ULL << b);
                ++nk2;
                cand &= ~__shfl(row, b, 64);
            }
            // append kept in rank order (kb identical across wave-0 lanes)
            if ((kb >> lane) & 1ULL) {
                int pos = nk_base + __popcll(kb & ((1ULL << lane) - 1ULL));
                kbox[pos]  = cbox[p][lane];
                karea[pos] = ca[p][lane];
            }
            if (lane == 0) { keepw[c] = kb; s_nkept = nk2; }
        } else if (w == 1) {
            // --- stage next chunk concurrently with resolve
            int nb = base + 64 + lane;
            float4 b = make_float4(0.f, 0.f, 0.f, 0.f);
            if (nb < V) b = topBoxes[nb];
            cbox[p ^ 1][lane] = b;
            ca[p ^ 1][lane]   = (b.z - b.x + 1.f) * (b.w - b.y + 1.f);
            intra[p ^ 1][lane] = 0;
        }
        __syncthreads();                                   // B3: resolve+append+stage done
        if (s_nkept >= NOUT) break;
    }

    const int n1 = s_nkept;
    for (int r = t; r < n1; r += 1024) {
        float4 b = kbox[r];
        out[r * 5 + 0] = 0.f;
        out[r * 5 + 1] = b.x; out[r * 5 + 2] = b.y;
        out[r * 5 + 3] = b.z; out[r * 5 + 4] = b.w;
    }
    // fallback: <300 kept -> fill with -inf ties (suppressed OR rank>=V), ascending rank.
    if (n1 < NOUT) {
        __syncthreads();
        const int per = 6;                     // 1024*6 >= 6000
        int r0 = t * per, r1 = min(r0 + per, KTOP);
        u32 cnt = 0;
        for (int r = r0; r < r1; ++r)
            cnt += ((keepw[r >> 6] >> (r & 63)) & 1ULL) ? 0u : 1u;
        scanbuf[t] = cnt;
        __syncthreads();
        for (int d = 1; d < 1024; d <<= 1) {
            u32 v = (t >= d) ? scanbuf[t - d] : 0;
            __syncthreads();
            scanbuf[t] += v;
            __syncthreads();
        }
        int ord = n1 + (int)(scanbuf[t] - cnt);   // exclusive prefix of not-kept
        for (int r = r0; r < r1 && ord < NOUT; ++r) {
            if (!((keepw[r >> 6] >> (r & 63)) & 1ULL)) {
                float4 b = topBoxes[r];
                out[ord * 5 + 0] = 0.f;
                out[ord * 5 + 1] = b.x; out[ord * 5 + 2] = b.y;
                out[ord * 5 + 3] = b.z; out[ord * 5 + 4] = b.w;
                ++ord;
            }
        }
    }
}

extern "C" void kernel_launch(void* const* d_in, const int* in_sizes, int n_in,
                              void* d_out, int out_size, void* d_ws, size_t ws_size,
                              hipStream_t stream) {
    const float* cls = (const float*)d_in[0];   // (1,64,64,18) f32
    const float* dlt = (const float*)d_in[1];   // (1,64,64,36) f32
    float* out = (float*)d_out;                 // 300x5 f32
    char* ws = (char*)d_ws;
    // layout (16B-aligned offsets); hist and cursor adjacent -> single memset
    u64*    keys     = (u64*)   (ws);                    // 294912
    u64*    scat     = (u64*)   (ws + 294912);           // 294912
    float4* boxes    = (float4*)(ws + 589824);           // 589824
    float4* topBoxes = (float4*)(ws + 1179648);          // 96000
    u32*    hist     = (u32*)   (ws + 1275648);          // 32768
    u32*    cursor   = (u32*)   (ws + 1308416);          // 32768
    u32*    binStart = (u32*)   (ws + 1341184);          // 32768
    u32*    gEV      = (u32*)   (ws + 1373952);          // [0]=E, [1]=V

    hipMemsetAsync(hist, 0, 2 * NBIN * sizeof(u32), stream);   // hist + cursor
    proposal_kernel<<<36, 1024, 0, stream>>>(cls, dlt, keys, boxes, hist);
    scan_kernel<<<1, 1024, 0, stream>>>(hist, binStart, gEV);
    scatter_kernel<<<(N_ANCH + 255) / 256, 256, 0, stream>>>(keys, binStart, cursor, scat);
    rank_kernel<<<(N_ANCH + 255) / 256, 256, 0, stream>>>(scat, binStart, hist, boxes, gEV,
                                                          topBoxes, (int*)&gEV[1]);
    nms_out_kernel<<<1, 1024, 0, stream>>>(topBoxes, gEV, out);
}